// Round 2
// baseline (412.007 us; speedup 1.0000x reference)
//
#include <hip/hip_runtime.h>
#include <hip/hip_bf16.h>

#define NN 8192
#define NE 262144
#define EPSF 1e-9f

typedef __attribute__((ext_vector_type(8))) short short8;
typedef __attribute__((ext_vector_type(4))) float floatx4;

// ---- CSR build (by dst), reused by both conv layers ----
__global__ __launch_bounds__(256) void degcount_kernel(const int* __restrict__ ei,
    int* __restrict__ deg) {
  int e = blockIdx.x * 256 + threadIdx.x;     // NE threads
  atomicAdd(&deg[ei[NE + e]], 1);
}

// single block: exclusive scan of 8192 degrees -> rowptr[8193], cursor copy
// log-time: per-thread sum of 32, wave shuffle-scan, 4 wave offsets via LDS.
__global__ __launch_bounds__(256) void scan_kernel(const int* __restrict__ deg,
    int* __restrict__ rowptr, int* __restrict__ cursor) {
  __shared__ int wsum[4];
  int t = threadIdx.x;
  int lane = t & 63, w = t >> 6;
  int base = t * 32;
  int local[32];
  int s = 0;
#pragma unroll
  for (int i = 0; i < 32; ++i) { local[i] = deg[base + i]; s += local[i]; }
  int sc = s;                                  // inclusive scan of s within wave
#pragma unroll
  for (int d = 1; d < 64; d <<= 1) {
    int v = __shfl_up(sc, d);
    if (lane >= d) sc += v;
  }
  if (lane == 63) wsum[w] = sc;
  __syncthreads();
  int woff = 0;
  for (int u = 0; u < w; ++u) woff += wsum[u];
  int run = woff + sc - s;                     // exclusive prefix for this thread
#pragma unroll
  for (int i = 0; i < 32; ++i) {
    rowptr[base + i] = run;
    cursor[base + i] = run;
    run += local[i];
  }
  if (t == 255) rowptr[NN] = run;              // == NE
}

__global__ __launch_bounds__(256) void scatter_kernel(const int* __restrict__ ei,
    int* __restrict__ cursor, int2* __restrict__ csr) {
  int e = blockIdx.x * 256 + threadIdx.x;     // NE threads
  int s = ei[e], d = ei[NE + e];
  int pos = atomicAdd(&cursor[d], 1);
  csr[pos] = (int2){e, s};
}

// ---- layer 1 fused: embed-gather + edge MLP + aggregate + node GEMM + leaky ----
// wave per node; lane covers cols {lane, lane+64}. h0 never materialized:
// emb (10 KB) and x (32 KB) are L1-resident, so the per-edge gather is L1-latency.
__global__ __launch_bounds__(256) void fused1_kernel(const int* __restrict__ rowptr,
    const int2* __restrict__ csr, const float* __restrict__ ea,
    const float* __restrict__ E1w, const float* __restrict__ E1b,
    const float* __restrict__ W1, const float* __restrict__ b1,
    const int* __restrict__ x, const float* __restrict__ emb,
    float* __restrict__ h1) {
  __shared__ float sE[16 * 128];
  __shared__ float sEb[128];
  __shared__ float st[4][128];
  for (int i = threadIdx.x; i < 16 * 128; i += 256) sE[i] = E1w[i];
  if (threadIdx.x < 128) sEb[threadIdx.x] = E1b[threadIdx.x];
  __syncthreads();
  int lane = threadIdx.x & 63;
  int w = threadIdx.x >> 6;
  int n = blockIdx.x * 4 + w;                 // 2048 blocks * 4 waves = 8192 nodes
  int beg = __builtin_amdgcn_readfirstlane(rowptr[n]);
  int end = __builtin_amdgcn_readfirstlane(rowptr[n + 1]);
  float acc0 = 0.f, acc1 = 0.f;
  int i = beg;
  for (; i + 4 <= end; i += 4) {              // 4-edge software pipeline
    int2 p0 = csr[i], p1 = csr[i + 1], p2 = csr[i + 2], p3 = csr[i + 3];
    int e0 = __builtin_amdgcn_readfirstlane(p0.x);
    int s0 = __builtin_amdgcn_readfirstlane(p0.y);
    int e1 = __builtin_amdgcn_readfirstlane(p1.x);
    int s1 = __builtin_amdgcn_readfirstlane(p1.y);
    int e2 = __builtin_amdgcn_readfirstlane(p2.x);
    int s2 = __builtin_amdgcn_readfirstlane(p2.y);
    int e3 = __builtin_amdgcn_readfirstlane(p3.x);
    int s3 = __builtin_amdgcn_readfirstlane(p3.y);
    int x0 = x[s0], x1 = x[s1], x2 = x[s2], x3 = x[s3];   // scalar loads
    float hA0 = emb[x0 * 128 + lane], hA1 = emb[x0 * 128 + lane + 64];
    float hB0 = emb[x1 * 128 + lane], hB1 = emb[x1 * 128 + lane + 64];
    float hC0 = emb[x2 * 128 + lane], hC1 = emb[x2 * 128 + lane + 64];
    float hD0 = emb[x3 * 128 + lane], hD1 = emb[x3 * 128 + lane + 64];
    const float* ea0 = ea + (size_t)e0 * 16;
    const float* ea1 = ea + (size_t)e1 * 16;
    const float* ea2 = ea + (size_t)e2 * 16;
    const float* ea3 = ea + (size_t)e3 * 16;
    float A0 = sEb[lane], A1 = sEb[lane + 64];
    float B0 = A0, B1 = A1, C0 = A0, C1 = A1, D0 = A0, D1 = A1;
#pragma unroll
    for (int k = 0; k < 16; ++k) {
      float w0 = sE[k * 128 + lane], w1 = sE[k * 128 + lane + 64];
      A0 += ea0[k] * w0; A1 += ea0[k] * w1;
      B0 += ea1[k] * w0; B1 += ea1[k] * w1;
      C0 += ea2[k] * w0; C1 += ea2[k] * w1;
      D0 += ea3[k] * w0; D1 += ea3[k] * w1;
    }
    float mA0 = hA0 + A0, mA1 = hA1 + A1;
    float mB0 = hB0 + B0, mB1 = hB1 + B1;
    float mC0 = hC0 + C0, mC1 = hC1 + C1;
    float mD0 = hD0 + D0, mD1 = hD1 + D1;
    acc0 += (mA0 > 0.f ? mA0 : 0.f) + (mB0 > 0.f ? mB0 : 0.f)
          + (mC0 > 0.f ? mC0 : 0.f) + (mD0 > 0.f ? mD0 : 0.f);
    acc1 += (mA1 > 0.f ? mA1 : 0.f) + (mB1 > 0.f ? mB1 : 0.f)
          + (mC1 > 0.f ? mC1 : 0.f) + (mD1 > 0.f ? mD1 : 0.f);
  }
  for (; i < end; ++i) {
    int2 p = csr[i];
    int e = __builtin_amdgcn_readfirstlane(p.x);
    int s = __builtin_amdgcn_readfirstlane(p.y);
    int xs = x[s];
    float h_0 = emb[xs * 128 + lane];
    float h_1 = emb[xs * 128 + lane + 64];
    const float* eav = ea + (size_t)e * 16;
    float ee0 = sEb[lane], ee1 = sEb[lane + 64];
#pragma unroll
    for (int k = 0; k < 16; ++k) {
      ee0 += eav[k] * sE[k * 128 + lane];
      ee1 += eav[k] * sE[k * 128 + lane + 64];
    }
    float m0 = h_0 + ee0, m1 = h_1 + ee1;
    acc0 += m0 > 0.f ? m0 : 0.f;
    acc1 += m1 > 0.f ? m1 : 0.f;
  }
  int xn = x[n];
  st[w][lane]      = (1.0f + EPSF) * emb[xn * 128 + lane] + acc0;
  st[w][lane + 64] = (1.0f + EPSF) * emb[xn * 128 + lane + 64] + acc1;
  // same-wave LDS RAW: ordered by lgkmcnt, no barrier needed
  float o = b1[lane];
#pragma unroll 16
  for (int k = 0; k < 128; ++k) o += st[w][k] * W1[k * 64 + lane];
  h1[(size_t)n * 64 + lane] = o > 0.f ? o : 0.01f * o;
}

// ---- layer 2 fused: same structure, 64-wide hidden, 32-wide bf16 output ----
__global__ __launch_bounds__(256) void fused2_kernel(const int* __restrict__ rowptr,
    const int2* __restrict__ csr, const float* __restrict__ ea,
    const float* __restrict__ E2w, const float* __restrict__ E2b,
    const float* __restrict__ W2, const float* __restrict__ b2,
    const float* __restrict__ h1, short* __restrict__ h2) {
  __shared__ float sE[16 * 64];
  __shared__ float sEb[64];
  __shared__ float st[4][64];
  for (int i = threadIdx.x; i < 16 * 64; i += 256) sE[i] = E2w[i];
  if (threadIdx.x < 64) sEb[threadIdx.x] = E2b[threadIdx.x];
  __syncthreads();
  int lane = threadIdx.x & 63;
  int w = threadIdx.x >> 6;
  int n = blockIdx.x * 4 + w;
  int beg = __builtin_amdgcn_readfirstlane(rowptr[n]);
  int end = __builtin_amdgcn_readfirstlane(rowptr[n + 1]);
  float acc = 0.f;
  int i = beg;
  for (; i + 4 <= end; i += 4) {
    int2 p0 = csr[i], p1 = csr[i + 1], p2 = csr[i + 2], p3 = csr[i + 3];
    int e0 = __builtin_amdgcn_readfirstlane(p0.x);
    int s0 = __builtin_amdgcn_readfirstlane(p0.y);
    int e1 = __builtin_amdgcn_readfirstlane(p1.x);
    int s1 = __builtin_amdgcn_readfirstlane(p1.y);
    int e2 = __builtin_amdgcn_readfirstlane(p2.x);
    int s2 = __builtin_amdgcn_readfirstlane(p2.y);
    int e3 = __builtin_amdgcn_readfirstlane(p3.x);
    int s3 = __builtin_amdgcn_readfirstlane(p3.y);
    float hA = h1[(size_t)s0 * 64 + lane];
    float hB = h1[(size_t)s1 * 64 + lane];
    float hC = h1[(size_t)s2 * 64 + lane];
    float hD = h1[(size_t)s3 * 64 + lane];
    const float* ea0 = ea + (size_t)e0 * 16;
    const float* ea1 = ea + (size_t)e1 * 16;
    const float* ea2 = ea + (size_t)e2 * 16;
    const float* ea3 = ea + (size_t)e3 * 16;
    float A = sEb[lane], B = A, C = A, D = A;
#pragma unroll
    for (int k = 0; k < 16; ++k) {
      float wv = sE[k * 64 + lane];
      A += ea0[k] * wv;
      B += ea1[k] * wv;
      C += ea2[k] * wv;
      D += ea3[k] * wv;
    }
    float mA = hA + A, mB = hB + B, mC = hC + C, mD = hD + D;
    acc += (mA > 0.f ? mA : 0.f) + (mB > 0.f ? mB : 0.f)
         + (mC > 0.f ? mC : 0.f) + (mD > 0.f ? mD : 0.f);
  }
  for (; i < end; ++i) {
    int2 p = csr[i];
    int e = __builtin_amdgcn_readfirstlane(p.x);
    int s = __builtin_amdgcn_readfirstlane(p.y);
    float hv = h1[(size_t)s * 64 + lane];
    const float* eav = ea + (size_t)e * 16;
    float ee = sEb[lane];
#pragma unroll
    for (int k = 0; k < 16; ++k) ee += eav[k] * sE[k * 64 + lane];
    float m = hv + ee;
    acc += m > 0.f ? m : 0.f;
  }
  st[w][lane] = (1.0f + EPSF) * h1[(size_t)n * 64 + lane] + acc;
  int col = lane & 31;
  float o = b2[col];
#pragma unroll 16
  for (int k = 0; k < 64; ++k) o += st[w][k] * W2[k * 32 + col];
  if (lane < 32) {
    unsigned u = __builtin_bit_cast(unsigned, o);
    u += 0x7fffu + ((u >> 16) & 1u);          // round-to-nearest-even
    h2[(size_t)n * 32 + col] = (short)(u >> 16);
  }
}

// out = H2 @ H2^T, H2: 8192x32 bf16. One wave -> 16 rows x 64 cols (4 MFMA tiles).
// LDS-transpose epilogue: 4 x global_store_dwordx4 per wave (4 rows x 256 B chunks)
// instead of 16 scalar dword stores at 64 B granularity.
__global__ __launch_bounds__(256) void gemm_kernel(const short* __restrict__ h2,
    float* __restrict__ out) {
  __shared__ float tile[4][16 * 68];          // per-wave 16 rows x 68 (pad) floats
  int wid = (blockIdx.x * 256 + threadIdx.x) >> 6;  // 65536 waves
  int lane = threadIdx.x & 63;
  int w = threadIdx.x >> 6;
  int cg = wid & 127;    // col group of 64
  int rt = wid >> 7;     // row tile of 16
  int r = lane & 15, q = lane >> 4;
  short8 afrag = *(const short8*)(h2 + ((rt * 16 + r) * 32 + q * 8));
  floatx4 acc[4];
#pragma unroll
  for (int t = 0; t < 4; ++t) {
    short8 bfrag = *(const short8*)(h2 + ((cg * 64 + t * 16 + r) * 32 + q * 8));
    floatx4 z = {0.f, 0.f, 0.f, 0.f};
    acc[t] = __builtin_amdgcn_mfma_f32_16x16x32_bf16(afrag, bfrag, z, 0, 0, 0);
  }
  // C layout: value acc[t][reg] is at row q*4+reg, col t*16+r of the 16x64 tile.
  float* T = tile[w];
#pragma unroll
  for (int t = 0; t < 4; ++t)
#pragma unroll
    for (int reg = 0; reg < 4; ++reg)
      T[(q * 4 + reg) * 68 + t * 16 + r] = acc[t][reg];
  // same-wave LDS RAW (wave-private region): ordered by lgkmcnt, no barrier
#pragma unroll
  for (int j = 0; j < 4; ++j) {
    float4 v = *(const float4*)&T[(j * 4 + q) * 68 + r * 4];
    *(float4*)&out[(size_t)(rt * 16 + j * 4 + q) * NN + cg * 64 + r * 4] = v;
  }
}

extern "C" void kernel_launch(void* const* d_in, const int* in_sizes, int n_in,
                              void* d_out, int out_size, void* d_ws, size_t ws_size,
                              hipStream_t stream) {
  const int*   x   = (const int*)d_in[0];
  const int*   ei  = (const int*)d_in[1];
  const float* ea  = (const float*)d_in[2];
  const float* emb = (const float*)d_in[3];
  const float* W1  = (const float*)d_in[4];
  const float* b1  = (const float*)d_in[5];
  const float* E1w = (const float*)d_in[6];
  const float* E1b = (const float*)d_in[7];
  const float* W2  = (const float*)d_in[8];
  const float* b2  = (const float*)d_in[9];
  const float* E2w = (const float*)d_in[10];
  const float* E2b = (const float*)d_in[11];

  float* ws     = (float*)d_ws;
  float* h1     = ws;                        // 8192*64 = 524288 f (2 MB)
  short* h2     = (short*)(ws + 524288);     // 8192*32 bf16 = 65536 f slots
  int*   deg    = (int*)(ws + 589824);       // 8192
  int*   rowptr = (int*)(ws + 598016);       // 8193 (padded to 8704)
  int*   cursor = (int*)(ws + 606720);       // 8192
  int2*  csr    = (int2*)(ws + 614912);      // NE int2 = 524288 f slots (2 MB)

  hipMemsetAsync(deg, 0, NN * sizeof(int), stream);
  degcount_kernel<<<1024, 256, 0, stream>>>(ei, deg);
  scan_kernel<<<1, 256, 0, stream>>>(deg, rowptr, cursor);
  scatter_kernel<<<1024, 256, 0, stream>>>(ei, cursor, csr);
  fused1_kernel<<<2048, 256, 0, stream>>>(rowptr, csr, ea, E1w, E1b, W1, b1, x, emb, h1);
  fused2_kernel<<<2048, 256, 0, stream>>>(rowptr, csr, ea, E2w, E2b, W2, b2, h1, h2);
  gemm_kernel<<<16384, 256, 0, stream>>>(h2, (float*)d_out);
}

// Round 3
// 380.092 us; speedup vs baseline: 1.0840x; 1.0840x over previous
//
#include <hip/hip_runtime.h>
#include <hip/hip_bf16.h>

#define NN 8192
#define NE 262144
#define EPSF 1e-9f

typedef __attribute__((ext_vector_type(8))) short short8;
typedef __attribute__((ext_vector_type(4))) float floatx4;

// merged: h0[n][:] = emb[x[n]][:]  AND  deg histogram of dst
// 262144 threads serve both (NN*32 float4 copies == NE edges).
__global__ __launch_bounds__(256) void embed_deg_kernel(const int* __restrict__ x,
    const float* __restrict__ emb, float* __restrict__ h0,
    const int* __restrict__ ei, int* __restrict__ deg) {
  int tid = blockIdx.x * 256 + threadIdx.x;
  int n = tid >> 5, j = tid & 31;
  int xi = x[n];
  ((float4*)h0)[(size_t)n * 32 + j] = ((const float4*)emb)[xi * 32 + j];
  atomicAdd(&deg[ei[NE + tid]], 1);
}

// single block: exclusive scan of 8192 degrees -> rowptr[8193], cursor copy
// log-time: per-thread sum of 32, wave shuffle-scan, 4 wave offsets via LDS.
__global__ __launch_bounds__(256) void scan_kernel(const int* __restrict__ deg,
    int* __restrict__ rowptr, int* __restrict__ cursor) {
  __shared__ int wsum[4];
  int t = threadIdx.x;
  int lane = t & 63, w = t >> 6;
  int base = t * 32;
  int local[32];
  int s = 0;
#pragma unroll
  for (int i = 0; i < 32; ++i) { local[i] = deg[base + i]; s += local[i]; }
  int sc = s;                                  // inclusive scan of s within wave
#pragma unroll
  for (int d = 1; d < 64; d <<= 1) {
    int v = __shfl_up(sc, d);
    if (lane >= d) sc += v;
  }
  if (lane == 63) wsum[w] = sc;
  __syncthreads();
  int woff = 0;
  for (int u = 0; u < w; ++u) woff += wsum[u];
  int run = woff + sc - s;                     // exclusive prefix for this thread
#pragma unroll
  for (int i = 0; i < 32; ++i) {
    rowptr[base + i] = run;
    cursor[base + i] = run;
    run += local[i];
  }
  if (t == 255) rowptr[NN] = run;              // == NE
}

__global__ __launch_bounds__(256) void scatter_kernel(const int* __restrict__ ei,
    int* __restrict__ cursor, int2* __restrict__ csr) {
  int e = blockIdx.x * 256 + threadIdx.x;     // NE threads
  int s = ei[e], d = ei[NE + e];
  int pos = atomicAdd(&cursor[d], 1);
  csr[pos] = (int2){e, s};
}

// ---- layer 1 fused: per-node gather + edge MLP + aggregate + node GEMM + leaky ----
// wave per node; lane covers cols {lane, lane+64} of the 128-wide hidden.
// csr broadcast-load for group g+1 is prefetched before group g's FMA chain.
__global__ __launch_bounds__(256) void fused1_kernel(const int* __restrict__ rowptr,
    const int2* __restrict__ csr, const float* __restrict__ ea,
    const float* __restrict__ E1w, const float* __restrict__ E1b,
    const float* __restrict__ W1, const float* __restrict__ b1,
    const float* __restrict__ h0, float* __restrict__ h1) {
  __shared__ float sE[16 * 128];
  __shared__ float sEb[128];
  __shared__ float st[4][128];
  for (int i = threadIdx.x; i < 16 * 128; i += 256) sE[i] = E1w[i];
  if (threadIdx.x < 128) sEb[threadIdx.x] = E1b[threadIdx.x];
  __syncthreads();
  int lane = threadIdx.x & 63;
  int w = threadIdx.x >> 6;
  int n = blockIdx.x * 4 + w;                 // 2048 blocks * 4 waves = 8192 nodes
  int beg = rowptr[n], end = rowptr[n + 1];
  float acc0 = 0.f, acc1 = 0.f;
  int i = beg;
  int2 pa, pb;
  bool have = (i + 2 <= end);
  if (have) { pa = csr[i]; pb = csr[i + 1]; }
  while (have) {
    int eA = __builtin_amdgcn_readfirstlane(pa.x);
    int sA = __builtin_amdgcn_readfirstlane(pa.y);
    int eB = __builtin_amdgcn_readfirstlane(pb.x);
    int sB = __builtin_amdgcn_readfirstlane(pb.y);
    // issue current group's gathers immediately
    float hA0 = h0[(size_t)sA * 128 + lane];
    float hA1 = h0[(size_t)sA * 128 + lane + 64];
    float hB0 = h0[(size_t)sB * 128 + lane];
    float hB1 = h0[(size_t)sB * 128 + lane + 64];
    // prefetch next group's csr (8 B broadcast) before the FMA chain
    i += 2;
    have = (i + 2 <= end);
    if (have) { pa = csr[i]; pb = csr[i + 1]; }
    const float* eaA = ea + (size_t)eA * 16;
    const float* eaB = ea + (size_t)eB * 16;
    float eeA0 = sEb[lane], eeA1 = sEb[lane + 64];
    float eeB0 = eeA0, eeB1 = eeA1;
#pragma unroll
    for (int k = 0; k < 16; ++k) {
      float w0 = sE[k * 128 + lane], w1 = sE[k * 128 + lane + 64];
      eeA0 += eaA[k] * w0; eeA1 += eaA[k] * w1;
      eeB0 += eaB[k] * w0; eeB1 += eaB[k] * w1;
    }
    float mA0 = hA0 + eeA0, mA1 = hA1 + eeA1;
    float mB0 = hB0 + eeB0, mB1 = hB1 + eeB1;
    acc0 += (mA0 > 0.f ? mA0 : 0.f) + (mB0 > 0.f ? mB0 : 0.f);
    acc1 += (mA1 > 0.f ? mA1 : 0.f) + (mB1 > 0.f ? mB1 : 0.f);
  }
  for (; i < end; ++i) {
    int2 p = csr[i];
    int e = __builtin_amdgcn_readfirstlane(p.x);
    int s = __builtin_amdgcn_readfirstlane(p.y);
    float h_0 = h0[(size_t)s * 128 + lane];
    float h_1 = h0[(size_t)s * 128 + lane + 64];
    const float* eav = ea + (size_t)e * 16;
    float ee0 = sEb[lane], ee1 = sEb[lane + 64];
#pragma unroll
    for (int k = 0; k < 16; ++k) {
      ee0 += eav[k] * sE[k * 128 + lane];
      ee1 += eav[k] * sE[k * 128 + lane + 64];
    }
    float m0 = h_0 + ee0, m1 = h_1 + ee1;
    acc0 += m0 > 0.f ? m0 : 0.f;
    acc1 += m1 > 0.f ? m1 : 0.f;
  }
  st[w][lane]      = (1.0f + EPSF) * h0[(size_t)n * 128 + lane] + acc0;
  st[w][lane + 64] = (1.0f + EPSF) * h0[(size_t)n * 128 + lane + 64] + acc1;
  // same-wave LDS RAW: DS ops issue in order within a wave, no barrier needed
  float o = b1[lane];
#pragma unroll 16
  for (int k = 0; k < 128; ++k) o += st[w][k] * W1[k * 64 + lane];
  h1[(size_t)n * 64 + lane] = o > 0.f ? o : 0.01f * o;
}

// ---- layer 2 fused: same structure, 64-wide hidden, 32-wide bf16 output ----
__global__ __launch_bounds__(256) void fused2_kernel(const int* __restrict__ rowptr,
    const int2* __restrict__ csr, const float* __restrict__ ea,
    const float* __restrict__ E2w, const float* __restrict__ E2b,
    const float* __restrict__ W2, const float* __restrict__ b2,
    const float* __restrict__ h1, short* __restrict__ h2) {
  __shared__ float sE[16 * 64];
  __shared__ float sEb[64];
  __shared__ float st[4][64];
  for (int i = threadIdx.x; i < 16 * 64; i += 256) sE[i] = E2w[i];
  if (threadIdx.x < 64) sEb[threadIdx.x] = E2b[threadIdx.x];
  __syncthreads();
  int lane = threadIdx.x & 63;
  int w = threadIdx.x >> 6;
  int n = blockIdx.x * 4 + w;
  int beg = rowptr[n], end = rowptr[n + 1];
  float acc = 0.f;
  int i = beg;
  int2 pa, pb;
  bool have = (i + 2 <= end);
  if (have) { pa = csr[i]; pb = csr[i + 1]; }
  while (have) {
    int eA = __builtin_amdgcn_readfirstlane(pa.x);
    int sA = __builtin_amdgcn_readfirstlane(pa.y);
    int eB = __builtin_amdgcn_readfirstlane(pb.x);
    int sB = __builtin_amdgcn_readfirstlane(pb.y);
    float hA = h1[(size_t)sA * 64 + lane];
    float hB = h1[(size_t)sB * 64 + lane];
    i += 2;
    have = (i + 2 <= end);
    if (have) { pa = csr[i]; pb = csr[i + 1]; }
    const float* eaA = ea + (size_t)eA * 16;
    const float* eaB = ea + (size_t)eB * 16;
    float eeA = sEb[lane], eeB = eeA;
#pragma unroll
    for (int k = 0; k < 16; ++k) {
      float wv = sE[k * 64 + lane];
      eeA += eaA[k] * wv;
      eeB += eaB[k] * wv;
    }
    float mA = hA + eeA, mB = hB + eeB;
    acc += (mA > 0.f ? mA : 0.f) + (mB > 0.f ? mB : 0.f);
  }
  for (; i < end; ++i) {
    int2 p = csr[i];
    int e = __builtin_amdgcn_readfirstlane(p.x);
    int s = __builtin_amdgcn_readfirstlane(p.y);
    float hv = h1[(size_t)s * 64 + lane];
    const float* eav = ea + (size_t)e * 16;
    float ee = sEb[lane];
#pragma unroll
    for (int k = 0; k < 16; ++k) ee += eav[k] * sE[k * 64 + lane];
    float m = hv + ee;
    acc += m > 0.f ? m : 0.f;
  }
  st[w][lane] = (1.0f + EPSF) * h1[(size_t)n * 64 + lane] + acc;
  int col = lane & 31;
  float o = b2[col];
#pragma unroll 16
  for (int k = 0; k < 64; ++k) o += st[w][k] * W2[k * 32 + col];
  if (lane < 32) {
    unsigned u = __builtin_bit_cast(unsigned, o);
    u += 0x7fffu + ((u >> 16) & 1u);          // round-to-nearest-even
    h2[(size_t)n * 32 + col] = (short)(u >> 16);
  }
}

// out = H2 @ H2^T, H2: 8192x32 bf16. One wave -> 16 rows x 64 cols (4 MFMA tiles).
// A frag: A[m=lane&15][k=(lane>>4)*8 + j]; B frag: B[k][n=lane&15] (same load pattern
// from H2 since B = H2^T). C/D: col=lane&15, row=(lane>>4)*4+reg.
__global__ __launch_bounds__(256) void gemm_kernel(const short* __restrict__ h2,
    float* __restrict__ out) {
  int wid = (blockIdx.x * 256 + threadIdx.x) >> 6;  // 65536 waves
  int lane = threadIdx.x & 63;
  int cg = wid & 127;    // col group of 64
  int rt = wid >> 7;     // row tile of 16
  int r = lane & 15, q = lane >> 4;
  short8 afrag = *(const short8*)(h2 + ((rt * 16 + r) * 32 + q * 8));
  floatx4 acc[4];
#pragma unroll
  for (int t = 0; t < 4; ++t) {
    short8 bfrag = *(const short8*)(h2 + ((cg * 64 + t * 16 + r) * 32 + q * 8));
    floatx4 z = {0.f, 0.f, 0.f, 0.f};
    acc[t] = __builtin_amdgcn_mfma_f32_16x16x32_bf16(afrag, bfrag, z, 0, 0, 0);
  }
  int row_base = rt * 16 + q * 4;
  int col_base = cg * 64 + r;
#pragma unroll
  for (int t = 0; t < 4; ++t)
#pragma unroll
    for (int reg = 0; reg < 4; ++reg)
      out[(size_t)(row_base + reg) * NN + col_base + t * 16] = acc[t][reg];
}

extern "C" void kernel_launch(void* const* d_in, const int* in_sizes, int n_in,
                              void* d_out, int out_size, void* d_ws, size_t ws_size,
                              hipStream_t stream) {
  const int*   x   = (const int*)d_in[0];
  const int*   ei  = (const int*)d_in[1];
  const float* ea  = (const float*)d_in[2];
  const float* emb = (const float*)d_in[3];
  const float* W1  = (const float*)d_in[4];
  const float* b1  = (const float*)d_in[5];
  const float* E1w = (const float*)d_in[6];
  const float* E1b = (const float*)d_in[7];
  const float* W2  = (const float*)d_in[8];
  const float* b2  = (const float*)d_in[9];
  const float* E2w = (const float*)d_in[10];
  const float* E2b = (const float*)d_in[11];

  float* ws     = (float*)d_ws;
  float* h0     = ws;                        // 8192*128 = 1048576 f (4 MB)
  float* h1     = ws + 1048576;              // 8192*64  = 524288 f  (2 MB)
  short* h2     = (short*)(ws + 1572864);    // 8192*32 bf16
  int*   deg    = (int*)(ws + 1703936);      // 8192
  int*   rowptr = (int*)(ws + 1712128);      // 8193 (padded)
  int*   cursor = (int*)(ws + 1720832);      // 8192
  int2*  csr    = (int2*)(ws + 1729024);     // NE int2 (2 MB)

  hipMemsetAsync(deg, 0, NN * sizeof(int), stream);
  embed_deg_kernel<<<1024, 256, 0, stream>>>(x, emb, h0, ei, deg);
  scan_kernel<<<1, 256, 0, stream>>>(deg, rowptr, cursor);
  scatter_kernel<<<1024, 256, 0, stream>>>(ei, cursor, csr);
  fused1_kernel<<<2048, 256, 0, stream>>>(rowptr, csr, ea, E1w, E1b, W1, b1, h0, h1);
  fused2_kernel<<<2048, 256, 0, stream>>>(rowptr, csr, ea, E2w, E2b, W2, b2, h1, h2);
  gemm_kernel<<<16384, 256, 0, stream>>>(h2, (float*)d_out);
}